// Round 2
// baseline (199.064 us; speedup 1.0000x reference)
//
#include <hip/hip_runtime.h>

#define S_ROWS 524288
#define D_COLS 63
#define TILE_ROWS 128
#define TILE_ELEMS (TILE_ROWS * D_COLS)   // 8064
#define TILE_VEC4 (TILE_ELEMS / 4)        // 2016
#define ROW_PAD 68                        // padded LDS row stride (floats), 272B, 16B-aligned
#define BLOCK 256
#define GRID 1024
#define NACC 30
#define POSW 0.2f

// gate flag bits
#define F_CUB  1u
#define F_CUB2 2u
#define F_AP   4u
#define F_REF  8u
#define F_TR   16u
#define F_SQ   32u

enum {
  A_CMD_LOSS = 0, A_CMDC, A_MAE1, A_MAE2, A_MAE4, A_MAE5,
  A_CE_AP, A_CUBC,
  A_REF_AX_CE, A_REF_CUB_CE, A_REF_AXC, A_REF_CUBC,
  A_TR_AX_CE, A_TR_CUB_CE, A_TR_AXC, A_TR_CUBC,
  A_SQ_CUB_CE, A_FACE_CE, A_SQ_CUBC, A_FACEC,
  A_BCE, A_NPOS, A_NNEG, A_POSC, A_NEGC,
  A_NA, A_NC, A_NREF, A_NTR, A_NSQ
};

__device__ __forceinline__ float logsig(float x) {
  float ax = fabsf(x);
  return fminf(x, 0.f) - __logf(1.f + __expf(-ax));
}

// operates on register arrays with literal bounds -> fully unrolled, reg-resident
__device__ __forceinline__ void slice_stats(const float* pr, const float* tr,
                                            int a, int b,
                                            int& targ, int& parg,
                                            float& lse, float& p_at_t) {
  float tmax = tr[a]; int ti = a;
  float pmax = pr[a]; int pi = a;
  #pragma unroll
  for (int j = a + 1; j < b; ++j) {
    float tv = tr[j]; if (tv > tmax) { tmax = tv; ti = j; }
    float pv = pr[j]; if (pv > pmax) { pmax = pv; pi = j; }
  }
  float se = 0.f;
  #pragma unroll
  for (int j = a; j < b; ++j) se += __expf(pr[j] - pmax);
  lse = pmax + __logf(se);
  targ = ti - a;
  parg = pi - a;
  p_at_t = pr[ti];
}

__global__ void init_ws(float* ws) {
  int i = threadIdx.x;
  if (i < NACC) ws[i] = 0.f;
  unsigned* wu = (unsigned*)ws;
  if (i == NACC) wu[NACC] = 0xFFFFFFFFu;
  if (i == NACC + 1) wu[NACC + 1] = 0u;
}

__launch_bounds__(BLOCK, 2)
__global__ void prog_loss_main(const float* __restrict__ P,
                               const float* __restrict__ T,
                               const float* __restrict__ W,
                               float* __restrict__ ws) {
  __shared__ float sp[TILE_ROWS * ROW_PAD];
  __shared__ float st[TILE_ROWS * ROW_PAD];
  __shared__ int scmd[TILE_ROWS];
  __shared__ float sred[4][NACC];
  __shared__ unsigned sflags[4];
  __shared__ unsigned smin[4];

  const int tid = threadIdx.x;
  const int lane = tid & 63;
  const int wave = tid >> 6;

  float acc[NACC];
  #pragma unroll
  for (int v = 0; v < NACC; ++v) acc[v] = 0.f;
  unsigned fl = 0u;
  unsigned mymin = 0xFFFFFFFFu;

  const int n_tiles = S_ROWS / TILE_ROWS;
  for (int tile = blockIdx.x; tile < n_tiles; tile += gridDim.x) {
    const size_t base = (size_t)tile * TILE_ELEMS;

    // ---- cmd pre-pass: argmax T[:, :7] straight from global (7 scalar loads/row)
    if (tid < TILE_ROWS) {
      const float* trow = T + base + (size_t)tid * D_COLS;
      float tm = trow[0]; int ti = 0;
      #pragma unroll
      for (int j = 1; j < 7; ++j) {
        float tv = trow[j];
        if (tv > tm) { tm = tv; ti = j; }
      }
      scmd[tid] = ti;
    }

    // ---- stage P,T -> padded LDS (coalesced f4 load, 4x scalar ds_write scatter)
    {
      const float4* P4 = (const float4*)(P + base);
      const float4* T4 = (const float4*)(T + base);
      #pragma unroll
      for (int k = 0; k < 8; ++k) {
        int i = tid + k * BLOCK;
        if (i < TILE_VEC4) {
          float4 a = P4[i];
          float4 b = T4[i];
          float av[4] = {a.x, a.y, a.z, a.w};
          float bv[4] = {b.x, b.y, b.z, b.w};
          int e0 = i * 4;
          #pragma unroll
          for (int q = 0; q < 4; ++q) {
            unsigned e = (unsigned)(e0 + q);
            unsigned row = e / 63u;
            unsigned col = e - row * 63u;
            unsigned idx = row * ROW_PAD + col;
            sp[idx] = av[q];
            st[idx] = bv[q];
          }
        }
      }
    }
    __syncthreads();

    if (tid < TILE_ROWS) {
      // ================= phase A: per-row stats, full row in registers =================
      float p[64], t[64];
      {
        const float4* prow = (const float4*)(sp + tid * ROW_PAD);
        const float4* trow = (const float4*)(st + tid * ROW_PAD);
        #pragma unroll
        for (int k = 0; k < 16; ++k) {
          float4 a = prow[k];
          float4 b = trow[k];
          p[4*k+0] = a.x; p[4*k+1] = a.y; p[4*k+2] = a.z; p[4*k+3] = a.w;
          t[4*k+0] = b.x; t[4*k+1] = b.y; t[4*k+2] = b.z; t[4*k+3] = b.w;
        }
      }
      const unsigned gr = (unsigned)(tile * TILE_ROWS + tid);

      int c, pc;   float lseA, pA; slice_stats(p, t, 0, 7,  c,  pc,  lseA, pA);
      int c1, pc1; float lseB, pB; slice_stats(p, t, 7, 18, c1, pc1, lseB, pB);
      int c2, pc2; float lseC, pC; slice_stats(p, t, 18, 29, c2, pc2, lseC, pC);
      int c3, pc3; float lseD, pD; slice_stats(p, t, 29, 40, c3, pc3, lseD, pD);
      int ax, pax; float lseE, pE; slice_stats(p, t, 49, 52, ax, pax, lseE, pE);
      int fc, pfc; float lseF, pF; slice_stats(p, t, 54, 60, fc, pfc, lseF, pF);
      float x62 = p[62], t62 = t[62];

      acc[A_CMD_LOSS] += lseA - pA;
      acc[A_CMDC] += (c == pc) ? 1.f : 0.f;

      if (c == 1) {
        acc[A_NC] += 1.f;
        float bce = -(POSW * t62 * logsig(x62) + (1.f - t62) * logsig(-x62));
        acc[A_BCE] += bce;
        bool pos = (t62 == 1.f), neg = (t62 == 0.f);
        acc[A_NPOS] += pos ? 1.f : 0.f;
        acc[A_NNEG] += neg ? 1.f : 0.f;
        acc[A_POSC] += (pos && x62 > 0.f) ? 1.f : 0.f;
        acc[A_NEGC] += (neg && x62 <= 0.f) ? 1.f : 0.f;
        if (gr >= 1u) fl |= F_CUB;
        if (gr >= 2u) fl |= F_CUB2;
        mymin = (gr < mymin) ? gr : mymin;
      } else if (c == 2) {
        acc[A_NA] += 1.f;
        acc[A_CUBC] += (pc1 == c1 && pc2 == c2) ? 1.f : 0.f;
        acc[A_CE_AP] += (lseB - pB) + (lseC - pC);
        if (gr >= 1u) fl |= F_AP;
      } else if (c == 3) {
        acc[A_NREF] += 1.f;
        acc[A_REF_AX_CE] += lseE - pE;
        acc[A_REF_CUB_CE] += lseB - pB;
        acc[A_REF_AXC] += (pax == ax) ? 1.f : 0.f;
        acc[A_REF_CUBC] += (pc1 == c1) ? 1.f : 0.f;
        if (gr >= 1u) fl |= F_REF;
      } else if (c == 4) {
        acc[A_NTR] += 1.f;
        acc[A_TR_AX_CE] += lseE - pE;
        acc[A_TR_CUB_CE] += lseB - pB;
        acc[A_TR_AXC] += (pax == ax) ? 1.f : 0.f;
        acc[A_TR_CUBC] += (pc1 == c1) ? 1.f : 0.f;
        if (gr >= 1u) fl |= F_TR;
      } else if (c == 5) {
        acc[A_NSQ] += 1.f;
        acc[A_SQ_CUBC] += (pc1 == c1 && pc2 == c2 && pc3 == c3) ? 1.f : 0.f;
        acc[A_FACEC] += (fc == pfc) ? 1.f : 0.f;
        acc[A_SQ_CUB_CE] += (lseB - pB) + (lseC - pC) + (lseD - pD);
        acc[A_FACE_CE] += lseF - pF;
        if (gr >= 1u) fl |= F_SQ;
      }
    } else {
      // ================= phase B: masked MAE, all-global coalesced (L2-hot) ============
      const int bt = tid - TILE_ROWS;  // 0..127
      const float4* P4 = (const float4*)(P + base);
      const float4* T4 = (const float4*)(T + base);
      const float4* W4 = (const float4*)(W + base);
      #pragma unroll
      for (int k = 0; k < 16; ++k) {
        int i = bt + k * TILE_ROWS;
        if (i < TILE_VEC4) {
          float4 w = W4[i];
          float4 a = P4[i];
          float4 b = T4[i];
          float wv[4] = {w.x, w.y, w.z, w.w};
          float pv[4] = {a.x, a.y, a.z, a.w};
          float tv[4] = {b.x, b.y, b.z, b.w};
          int e0 = i * 4;
          #pragma unroll
          for (int q = 0; q < 4; ++q) {
            unsigned row = (unsigned)(e0 + q) / 63u;
            int c = scmd[row];
            float v = wv[q] * fabsf(pv[q] - tv[q]);
            acc[A_MAE1] += (c == 1) ? v : 0.f;
            acc[A_MAE2] += (c == 2) ? v : 0.f;
            acc[A_MAE4] += (c == 4) ? v : 0.f;
            acc[A_MAE5] += (c == 5) ? v : 0.f;
          }
        }
      }
    }
    __syncthreads();  // protect LDS before next tile's staging
  }

  // ---- reduction: wave shuffle -> LDS -> atomics ----
  #pragma unroll
  for (int v = 0; v < NACC; ++v) {
    float x = acc[v];
    #pragma unroll
    for (int off = 32; off > 0; off >>= 1) x += __shfl_down(x, off, 64);
    if (lane == 0) sred[wave][v] = x;
  }
  {
    unsigned f = fl, m = mymin;
    #pragma unroll
    for (int off = 32; off > 0; off >>= 1) {
      f |= __shfl_down(f, off, 64);
      unsigned om = __shfl_down(m, off, 64);
      m = (om < m) ? om : m;
    }
    if (lane == 0) { sflags[wave] = f; smin[wave] = m; }
  }
  __syncthreads();
  unsigned* wu = (unsigned*)ws;
  if (tid == 0) {
    unsigned f = sflags[0] | sflags[1] | sflags[2] | sflags[3];
    unsigned m = min(min(smin[0], smin[1]), min(smin[2], smin[3]));
    if (f) atomicOr(&wu[NACC + 1], f);
    if (m != 0xFFFFFFFFu) atomicMin(&wu[NACC], m);
  }
  if (tid < NACC) {
    float s = sred[0][tid] + sred[1][tid] + sred[2][tid] + sred[3][tid];
    atomicAdd(&ws[tid], s);
  }
}

__global__ void finalize_k(const float* __restrict__ ws,
                           const float* __restrict__ P,
                           const float* __restrict__ T,
                           float* __restrict__ out) {
  const unsigned* wu = (const unsigned*)ws;
  unsigned flags = wu[NACC + 1];
  unsigned fm = wu[NACC];
  bool g_cub  = (flags & F_CUB)  != 0;
  bool g_cub2 = (flags & F_CUB2) != 0;
  bool g_ap   = (flags & F_AP)   != 0;
  bool g_ref  = (flags & F_REF)  != 0;
  bool g_tr   = (flags & F_TR)   != 0;
  bool g_sq   = (flags & F_SQ)   != 0;
  unsigned first = (fm == 0xFFFFFFFFu) ? 0u : fm;
  float x62 = P[(size_t)first * D_COLS + 62];
  float t62 = T[(size_t)first * D_COLS + 62];
  float bce_f = -(POSW * t62 * logsig(x62) + (1.f - t62) * logsig(-x62));
  float pos_f  = (t62 == 1.f) ? 1.f : 0.f;
  float neg_f  = (t62 == 0.f) ? 1.f : 0.f;
  float posc_f = (t62 == 1.f && x62 > 0.f) ? 1.f : 0.f;
  float negc_f = (t62 == 0.f && x62 <= 0.f) ? 1.f : 0.f;

  out[0]  = ws[A_CMD_LOSS];
  out[1]  = g_cub ? ws[A_MAE1] : 0.f;
  out[2]  = g_ap  ? ws[A_MAE2] : 0.f;
  out[3]  = g_sq  ? ws[A_MAE5] : 0.f;
  out[4]  = g_tr  ? ws[A_MAE4] : 0.f;
  out[5]  = g_ap  ? ws[A_CE_AP] : 0.f;
  out[6]  = g_sq  ? ws[A_SQ_CUB_CE] : 0.f;
  out[7]  = (g_ref ? ws[A_REF_CUB_CE] : 0.f) + (g_tr ? ws[A_TR_CUB_CE] : 0.f);
  out[8]  = (g_ref ? ws[A_REF_AX_CE]  : 0.f) + (g_tr ? ws[A_TR_AX_CE]  : 0.f);
  out[9]  = g_sq ? ws[A_FACE_CE] : 0.f;
  out[10] = ws[A_CMDC];
  out[11] = g_ap ? ws[A_CUBC] : 0.f;
  out[12] = g_sq ? ws[A_SQ_CUBC] : 0.f;
  out[13] = (g_ref ? ws[A_REF_CUBC] : 0.f) + (g_tr ? ws[A_TR_CUBC] : 0.f);
  out[14] = (g_ref ? ws[A_REF_AXC]  : 0.f) + (g_tr ? ws[A_TR_AXC]  : 0.f);
  out[15] = g_sq ? ws[A_FACEC] : 0.f;
  out[16] = g_cub2 ? (ws[A_BCE]  - bce_f)  : 0.f;
  out[17] = g_cub2 ? (ws[A_POSC] - posc_f) : 0.f;
  out[18] = g_cub2 ? (ws[A_NEGC] - negc_f) : 0.f;
  out[19] = g_cub2 ? (ws[A_NNEG] - neg_f)  : 0.f;
  out[20] = g_cub2 ? (ws[A_NPOS] - pos_f)  : 0.f;
  out[21] = ws[A_NA];
  out[22] = ws[A_NC];
  out[23] = ws[A_NREF] + ws[A_NTR];
  out[24] = ws[A_NSQ];
}

extern "C" void kernel_launch(void* const* d_in, const int* in_sizes, int n_in,
                              void* d_out, int out_size, void* d_ws, size_t ws_size,
                              hipStream_t stream) {
  const float* P = (const float*)d_in[0];
  const float* T = (const float*)d_in[1];
  const float* W = (const float*)d_in[2];
  float* ws = (float*)d_ws;
  float* out = (float*)d_out;

  hipLaunchKernelGGL(init_ws, dim3(1), dim3(64), 0, stream, ws);
  hipLaunchKernelGGL(prog_loss_main, dim3(GRID), dim3(BLOCK), 0, stream, P, T, W, ws);
  hipLaunchKernelGGL(finalize_k, dim3(1), dim3(1), 0, stream, ws, P, T, out);
}

// Round 3
// 147.447 us; speedup vs baseline: 1.3501x; 1.3501x over previous
//
#include <hip/hip_runtime.h>

#define S_ROWS 524288
#define D_COLS 63
#define TILE_ROWS 64
#define TILE_ELEMS (TILE_ROWS * D_COLS)   // 4032
#define TILE_VEC4 (TILE_ELEMS / 4)        // 1008
#define BLOCK 256
#define GRID 2048
#define NACC 30
#define POSW 0.2f

// gate flag bits
#define F_CUB  1u
#define F_CUB2 2u
#define F_AP   4u
#define F_REF  8u
#define F_TR   16u
#define F_SQ   32u

enum {
  A_CMD_LOSS = 0, A_CMDC, A_MAE1, A_MAE2, A_MAE4, A_MAE5,
  A_CE_AP, A_CUBC,
  A_REF_AX_CE, A_REF_CUB_CE, A_REF_AXC, A_REF_CUBC,
  A_TR_AX_CE, A_TR_CUB_CE, A_TR_AXC, A_TR_CUBC,
  A_SQ_CUB_CE, A_FACE_CE, A_SQ_CUBC, A_FACEC,
  A_BCE, A_NPOS, A_NNEG, A_POSC, A_NEGC,
  A_NA, A_NC, A_NREF, A_NTR, A_NSQ
};

#define GLOAD_LDS16(gptr, lptr) \
  __builtin_amdgcn_global_load_lds( \
      (const __attribute__((address_space(1))) void*)(gptr), \
      (__attribute__((address_space(3))) void*)(lptr), 16, 0, 0)

__device__ __forceinline__ float logsig(float x) {
  float ax = fabsf(x);
  return fminf(x, 0.f) - __logf(1.f + __expf(-ax));
}

// reads directly from LDS row pointers; literal bounds -> unrolled, batched ds reads
__device__ __forceinline__ void slice_stats(const float* pr, const float* tr,
                                            int a, int b,
                                            int& targ, int& parg,
                                            float& lse, float& p_at_t) {
  float tmax = tr[a]; int ti = a;
  float pmax = pr[a]; int pi = a;
  #pragma unroll
  for (int j = a + 1; j < b; ++j) {
    float tv = tr[j]; if (tv > tmax) { tmax = tv; ti = j; }
    float pv = pr[j]; if (pv > pmax) { pmax = pv; pi = j; }
  }
  float se = 0.f;
  #pragma unroll
  for (int j = a; j < b; ++j) se += __expf(pr[j] - pmax);
  lse = pmax + __logf(se);
  targ = ti - a;
  parg = pi - a;
  p_at_t = pr[ti];
}

__global__ void init_ws(float* ws) {
  int i = threadIdx.x;
  if (i < NACC) ws[i] = 0.f;
  unsigned* wu = (unsigned*)ws;
  if (i == NACC) wu[NACC] = 0xFFFFFFFFu;
  if (i == NACC + 1) wu[NACC + 1] = 0u;
}

__launch_bounds__(BLOCK, 4)
__global__ void prog_loss_main(const float* __restrict__ P,
                               const float* __restrict__ T,
                               const float* __restrict__ W,
                               float* __restrict__ ws) {
  __shared__ float sp[TILE_ELEMS];
  __shared__ float st[TILE_ELEMS];
  __shared__ int scmd[TILE_ROWS];
  __shared__ float sred[4][NACC];
  __shared__ unsigned sflags[4];
  __shared__ unsigned smin[4];

  const int tid = threadIdx.x;
  const int lane = tid & 63;
  const int wave = tid >> 6;

  float acc[NACC];
  #pragma unroll
  for (int v = 0; v < NACC; ++v) acc[v] = 0.f;
  unsigned fl = 0u;
  unsigned mymin = 0xFFFFFFFFu;

  const int n_tiles = S_ROWS / TILE_ROWS;
  for (int tile = blockIdx.x; tile < n_tiles; tile += gridDim.x) {
    const size_t base = (size_t)tile * TILE_ELEMS;

    // ---- stage P,T -> LDS via global_load_lds (16B/lane, linear dest) ----
    {
      const float4* P4 = (const float4*)(P + base);
      const float4* T4 = (const float4*)(T + base);
      #pragma unroll
      for (int k = 0; k < 4; ++k) {
        int i = tid + k * BLOCK;              // f4 index; lane-contiguous per wave
        int chunk = (wave * 64) + k * BLOCK;  // wave-uniform LDS chunk base (f4)
        if (i < TILE_VEC4) {
          GLOAD_LDS16(&P4[i], (float4*)sp + chunk);
          GLOAD_LDS16(&T4[i], (float4*)st + chunk);
        }
      }
    }
    __syncthreads();

    // ---- phase A: per-row stats (threads 0..63, one row each) ----
    if (tid < TILE_ROWS) {
      const float* pr = sp + tid * D_COLS;
      const float* tr = st + tid * D_COLS;
      const unsigned gr = (unsigned)(tile * TILE_ROWS + tid);

      int c, pc;   float lseA, pA; slice_stats(pr, tr, 0, 7,  c,  pc,  lseA, pA);
      int c1, pc1; float lseB, pB; slice_stats(pr, tr, 7, 18, c1, pc1, lseB, pB);
      int c2, pc2; float lseC, pC; slice_stats(pr, tr, 18, 29, c2, pc2, lseC, pC);
      int c3, pc3; float lseD, pD; slice_stats(pr, tr, 29, 40, c3, pc3, lseD, pD);
      int ax, pax; float lseE, pE; slice_stats(pr, tr, 49, 52, ax, pax, lseE, pE);
      int fc, pfc; float lseF, pF; slice_stats(pr, tr, 54, 60, fc, pfc, lseF, pF);
      float x62 = pr[62], t62 = tr[62];

      acc[A_CMD_LOSS] += lseA - pA;
      acc[A_CMDC] += (c == pc) ? 1.f : 0.f;
      scmd[tid] = c;

      if (c == 1) {
        acc[A_NC] += 1.f;
        float bce = -(POSW * t62 * logsig(x62) + (1.f - t62) * logsig(-x62));
        acc[A_BCE] += bce;
        bool pos = (t62 == 1.f), neg = (t62 == 0.f);
        acc[A_NPOS] += pos ? 1.f : 0.f;
        acc[A_NNEG] += neg ? 1.f : 0.f;
        acc[A_POSC] += (pos && x62 > 0.f) ? 1.f : 0.f;
        acc[A_NEGC] += (neg && x62 <= 0.f) ? 1.f : 0.f;
        if (gr >= 1u) fl |= F_CUB;
        if (gr >= 2u) fl |= F_CUB2;
        mymin = (gr < mymin) ? gr : mymin;
      } else if (c == 2) {
        acc[A_NA] += 1.f;
        acc[A_CUBC] += (pc1 == c1 && pc2 == c2) ? 1.f : 0.f;
        acc[A_CE_AP] += (lseB - pB) + (lseC - pC);
        if (gr >= 1u) fl |= F_AP;
      } else if (c == 3) {
        acc[A_NREF] += 1.f;
        acc[A_REF_AX_CE] += lseE - pE;
        acc[A_REF_CUB_CE] += lseB - pB;
        acc[A_REF_AXC] += (pax == ax) ? 1.f : 0.f;
        acc[A_REF_CUBC] += (pc1 == c1) ? 1.f : 0.f;
        if (gr >= 1u) fl |= F_REF;
      } else if (c == 4) {
        acc[A_NTR] += 1.f;
        acc[A_TR_AX_CE] += lseE - pE;
        acc[A_TR_CUB_CE] += lseB - pB;
        acc[A_TR_AXC] += (pax == ax) ? 1.f : 0.f;
        acc[A_TR_CUBC] += (pc1 == c1) ? 1.f : 0.f;
        if (gr >= 1u) fl |= F_TR;
      } else if (c == 5) {
        acc[A_NSQ] += 1.f;
        acc[A_SQ_CUBC] += (pc1 == c1 && pc2 == c2 && pc3 == c3) ? 1.f : 0.f;
        acc[A_FACEC] += (fc == pfc) ? 1.f : 0.f;
        acc[A_SQ_CUB_CE] += (lseB - pB) + (lseC - pC) + (lseD - pD);
        acc[A_FACE_CE] += lseF - pF;
        if (gr >= 1u) fl |= F_SQ;
      }
    }
    __syncthreads();

    // ---- phase B: masked MAE (all 256 threads, f4-linear) ----
    {
      const float4* W4 = (const float4*)(W + base);
      const float4* sp4 = (const float4*)sp;
      const float4* st4 = (const float4*)st;
      #pragma unroll
      for (int k = 0; k < 4; ++k) {
        int i = tid + k * BLOCK;
        if (i < TILE_VEC4) {
          float4 w = W4[i];
          float4 p = sp4[i];
          float4 t = st4[i];
          int e0 = i * 4;
          unsigned r0 = (unsigned)e0 / 63u;
          unsigned r3 = (unsigned)(e0 + 3) / 63u;
          int c0 = scmd[r0];
          int c3 = (r3 != r0) ? scmd[r3] : c0;
          float wv[4] = {w.x, w.y, w.z, w.w};
          float pv[4] = {p.x, p.y, p.z, p.w};
          float tv[4] = {t.x, t.y, t.z, t.w};
          #pragma unroll
          for (int q = 0; q < 4; ++q) {
            unsigned row = (unsigned)(e0 + q) / 63u;
            int c = (row == r0) ? c0 : c3;
            float v = wv[q] * fabsf(pv[q] - tv[q]);
            acc[A_MAE1] += (c == 1) ? v : 0.f;
            acc[A_MAE2] += (c == 2) ? v : 0.f;
            acc[A_MAE4] += (c == 4) ? v : 0.f;
            acc[A_MAE5] += (c == 5) ? v : 0.f;
          }
        }
      }
    }
    __syncthreads();  // protect LDS before next tile's staging
  }

  // ---- reduction: wave shuffle -> LDS -> atomics ----
  #pragma unroll
  for (int v = 0; v < NACC; ++v) {
    float x = acc[v];
    #pragma unroll
    for (int off = 32; off > 0; off >>= 1) x += __shfl_down(x, off, 64);
    if (lane == 0) sred[wave][v] = x;
  }
  {
    unsigned f = fl, m = mymin;
    #pragma unroll
    for (int off = 32; off > 0; off >>= 1) {
      f |= __shfl_down(f, off, 64);
      unsigned om = __shfl_down(m, off, 64);
      m = (om < m) ? om : m;
    }
    if (lane == 0) { sflags[wave] = f; smin[wave] = m; }
  }
  __syncthreads();
  unsigned* wu = (unsigned*)ws;
  if (tid == 0) {
    unsigned f = sflags[0] | sflags[1] | sflags[2] | sflags[3];
    unsigned m = min(min(smin[0], smin[1]), min(smin[2], smin[3]));
    if (f) atomicOr(&wu[NACC + 1], f);
    if (m != 0xFFFFFFFFu) atomicMin(&wu[NACC], m);
  }
  if (tid < NACC) {
    float s = sred[0][tid] + sred[1][tid] + sred[2][tid] + sred[3][tid];
    atomicAdd(&ws[tid], s);
  }
}

__global__ void finalize_k(const float* __restrict__ ws,
                           const float* __restrict__ P,
                           const float* __restrict__ T,
                           float* __restrict__ out) {
  const unsigned* wu = (const unsigned*)ws;
  unsigned flags = wu[NACC + 1];
  unsigned fm = wu[NACC];
  bool g_cub  = (flags & F_CUB)  != 0;
  bool g_cub2 = (flags & F_CUB2) != 0;
  bool g_ap   = (flags & F_AP)   != 0;
  bool g_ref  = (flags & F_REF)  != 0;
  bool g_tr   = (flags & F_TR)   != 0;
  bool g_sq   = (flags & F_SQ)   != 0;
  unsigned first = (fm == 0xFFFFFFFFu) ? 0u : fm;
  float x62 = P[(size_t)first * D_COLS + 62];
  float t62 = T[(size_t)first * D_COLS + 62];
  float bce_f = -(POSW * t62 * logsig(x62) + (1.f - t62) * logsig(-x62));
  float pos_f  = (t62 == 1.f) ? 1.f : 0.f;
  float neg_f  = (t62 == 0.f) ? 1.f : 0.f;
  float posc_f = (t62 == 1.f && x62 > 0.f) ? 1.f : 0.f;
  float negc_f = (t62 == 0.f && x62 <= 0.f) ? 1.f : 0.f;

  out[0]  = ws[A_CMD_LOSS];
  out[1]  = g_cub ? ws[A_MAE1] : 0.f;
  out[2]  = g_ap  ? ws[A_MAE2] : 0.f;
  out[3]  = g_sq  ? ws[A_MAE5] : 0.f;
  out[4]  = g_tr  ? ws[A_MAE4] : 0.f;
  out[5]  = g_ap  ? ws[A_CE_AP] : 0.f;
  out[6]  = g_sq  ? ws[A_SQ_CUB_CE] : 0.f;
  out[7]  = (g_ref ? ws[A_REF_CUB_CE] : 0.f) + (g_tr ? ws[A_TR_CUB_CE] : 0.f);
  out[8]  = (g_ref ? ws[A_REF_AX_CE]  : 0.f) + (g_tr ? ws[A_TR_AX_CE]  : 0.f);
  out[9]  = g_sq ? ws[A_FACE_CE] : 0.f;
  out[10] = ws[A_CMDC];
  out[11] = g_ap ? ws[A_CUBC] : 0.f;
  out[12] = g_sq ? ws[A_SQ_CUBC] : 0.f;
  out[13] = (g_ref ? ws[A_REF_CUBC] : 0.f) + (g_tr ? ws[A_TR_CUBC] : 0.f);
  out[14] = (g_ref ? ws[A_REF_AXC]  : 0.f) + (g_tr ? ws[A_TR_AXC]  : 0.f);
  out[15] = g_sq ? ws[A_FACEC] : 0.f;
  out[16] = g_cub2 ? (ws[A_BCE]  - bce_f)  : 0.f;
  out[17] = g_cub2 ? (ws[A_POSC] - posc_f) : 0.f;
  out[18] = g_cub2 ? (ws[A_NEGC] - negc_f) : 0.f;
  out[19] = g_cub2 ? (ws[A_NNEG] - neg_f)  : 0.f;
  out[20] = g_cub2 ? (ws[A_NPOS] - pos_f)  : 0.f;
  out[21] = ws[A_NA];
  out[22] = ws[A_NC];
  out[23] = ws[A_NREF] + ws[A_NTR];
  out[24] = ws[A_NSQ];
}

extern "C" void kernel_launch(void* const* d_in, const int* in_sizes, int n_in,
                              void* d_out, int out_size, void* d_ws, size_t ws_size,
                              hipStream_t stream) {
  const float* P = (const float*)d_in[0];
  const float* T = (const float*)d_in[1];
  const float* W = (const float*)d_in[2];
  float* ws = (float*)d_ws;
  float* out = (float*)d_out;

  hipLaunchKernelGGL(init_ws, dim3(1), dim3(64), 0, stream, ws);
  hipLaunchKernelGGL(prog_loss_main, dim3(GRID), dim3(BLOCK), 0, stream, P, T, W, ws);
  hipLaunchKernelGGL(finalize_k, dim3(1), dim3(1), 0, stream, ws, P, T, out);
}

// Round 4
// 112.424 us; speedup vs baseline: 1.7707x; 1.3115x over previous
//
#include <hip/hip_runtime.h>

#define S_ROWS 524288
#define D_COLS 63
#define TILE_ROWS 64
#define TILE_ELEMS (TILE_ROWS * D_COLS)   // 4032
#define TILE_VEC4 (TILE_ELEMS / 4)        // 1008
#define BLOCK 256
#define GRID 512
#define TILES_PER_BLOCK (S_ROWS / (TILE_ROWS * GRID))  // 16
#define NACC 30
#define POSW 0.2f

// gate flag bits
#define F_CUB  1u
#define F_CUB2 2u
#define F_AP   4u
#define F_REF  8u
#define F_TR   16u
#define F_SQ   32u

enum {
  A_CMD_LOSS = 0, A_CMDC, A_MAE1, A_MAE2, A_MAE4, A_MAE5,
  A_CE_AP, A_CUBC,
  A_REF_AX_CE, A_REF_CUB_CE, A_REF_AXC, A_REF_CUBC,
  A_TR_AX_CE, A_TR_CUB_CE, A_TR_AXC, A_TR_CUBC,
  A_SQ_CUB_CE, A_FACE_CE, A_SQ_CUBC, A_FACEC,
  A_BCE, A_NPOS, A_NNEG, A_POSC, A_NEGC,
  A_NA, A_NC, A_NREF, A_NTR, A_NSQ
};

#define GLOAD_LDS16(gptr, lptr) \
  __builtin_amdgcn_global_load_lds( \
      (const __attribute__((address_space(1))) void*)(gptr), \
      (__attribute__((address_space(3))) void*)(lptr), 16, 0, 0)

__device__ __forceinline__ float logsig(float x) {
  float ax = fabsf(x);
  return fminf(x, 0.f) - __logf(1.f + __expf(-ax));
}

__device__ __forceinline__ void slice_stats(const float* pr, const float* tr,
                                            int a, int b,
                                            int& targ, int& parg,
                                            float& lse, float& p_at_t) {
  float tmax = tr[a]; int ti = a;
  float pmax = pr[a]; int pi = a;
  #pragma unroll
  for (int j = a + 1; j < b; ++j) {
    float tv = tr[j]; if (tv > tmax) { tmax = tv; ti = j; }
    float pv = pr[j]; if (pv > pmax) { pmax = pv; pi = j; }
  }
  float se = 0.f;
  #pragma unroll
  for (int j = a; j < b; ++j) se += __expf(pr[j] - pmax);
  lse = pmax + __logf(se);
  targ = ti - a;
  parg = pi - a;
  p_at_t = pr[ti];
}

__global__ void init_ws(float* ws) {
  int i = threadIdx.x;
  if (i < NACC) ws[i] = 0.f;
  unsigned* wu = (unsigned*)ws;
  if (i == NACC) wu[NACC] = 0xFFFFFFFFu;
  if (i == NACC + 1) wu[NACC + 1] = 0u;
}

__device__ __forceinline__ void stage_tile(const float* __restrict__ gP,
                                           const float* __restrict__ gT,
                                           float* lp, float* lt,
                                           int tid, int wave) {
  const float4* P4 = (const float4*)gP;
  const float4* T4 = (const float4*)gT;
  #pragma unroll
  for (int k = 0; k < 4; ++k) {
    int i = tid + k * BLOCK;
    int chunk = wave * 64 + k * BLOCK;  // wave-uniform LDS f4 base; HW adds lane*16B
    if (i < TILE_VEC4) {
      GLOAD_LDS16(&P4[i], (float4*)lp + chunk);
      GLOAD_LDS16(&T4[i], (float4*)lt + chunk);
    }
  }
}

__launch_bounds__(BLOCK, 2)
__global__ void prog_loss_main(const float* __restrict__ P,
                               const float* __restrict__ T,
                               const float* __restrict__ W,
                               float* __restrict__ ws) {
  __shared__ float sp[2][TILE_ELEMS];
  __shared__ float st[2][TILE_ELEMS];
  __shared__ int scmd[TILE_ROWS];
  __shared__ float sred[4][NACC];
  __shared__ unsigned sflags[4];
  __shared__ unsigned smin[4];

  const int tid = threadIdx.x;
  const int lane = tid & 63;
  const int wave = tid >> 6;

  float acc[NACC];
  #pragma unroll
  for (int v = 0; v < NACC; ++v) acc[v] = 0.f;
  unsigned fl = 0u;
  unsigned mymin = 0xFFFFFFFFu;

  const int tile0 = blockIdx.x * TILES_PER_BLOCK;

  // prologue: stage first tile into buffer 0 (vmcnt = 8 at loop entry)
  stage_tile(P + (size_t)tile0 * TILE_ELEMS, T + (size_t)tile0 * TILE_ELEMS,
             sp[0], st[0], tid, wave);

  for (int tt = 0; tt < TILES_PER_BLOCK; ++tt) {
    const int tile = tile0 + tt;
    const int cur = tt & 1;
    const size_t base = (size_t)tile * TILE_ELEMS;

    // ---- W loads for CURRENT tile -> regs (issued BEFORE next-tile DMA so
    //      the counted vmcnt(8) below also covers them) ----
    float4 wreg[4];
    {
      const float4* W4 = (const float4*)(W + base);
      #pragma unroll
      for (int k = 0; k < 4; ++k) {
        int i = tid + k * BLOCK;
        if (i < TILE_VEC4) wreg[k] = W4[i];
        else wreg[k] = make_float4(0.f, 0.f, 0.f, 0.f);
      }
    }
    asm volatile("" ::: "memory");  // pin W loads before the DMA issue

    // ---- issue NEXT tile's DMA into the other buffer; counted wait keeps it
    //      in flight across the barrier (never vmcnt(0) mid-loop) ----
    if (tt + 1 < TILES_PER_BLOCK) {
      const size_t nb = (size_t)(tile + 1) * TILE_ELEMS;
      stage_tile(P + nb, T + nb, sp[1 - cur], st[1 - cur], tid, wave);
      asm volatile("s_waitcnt vmcnt(8)" ::: "memory");
    } else {
      asm volatile("s_waitcnt vmcnt(0)" ::: "memory");
    }
    __builtin_amdgcn_sched_barrier(0);
    __builtin_amdgcn_s_barrier();

    // ---- phase A: per-row stats (wave 0, one row per lane) ----
    if (tid < TILE_ROWS) {
      const float* pr = sp[cur] + tid * D_COLS;
      const float* tr = st[cur] + tid * D_COLS;
      const unsigned gr = (unsigned)(tile * TILE_ROWS + tid);

      int c, pc;   float lseA, pA; slice_stats(pr, tr, 0, 7,  c,  pc,  lseA, pA);
      int c1, pc1; float lseB, pB; slice_stats(pr, tr, 7, 18, c1, pc1, lseB, pB);
      int c2, pc2; float lseC, pC; slice_stats(pr, tr, 18, 29, c2, pc2, lseC, pC);
      int c3, pc3; float lseD, pD; slice_stats(pr, tr, 29, 40, c3, pc3, lseD, pD);
      int ax, pax; float lseE, pE; slice_stats(pr, tr, 49, 52, ax, pax, lseE, pE);
      int fc, pfc; float lseF, pF; slice_stats(pr, tr, 54, 60, fc, pfc, lseF, pF);
      float x62 = pr[62], t62 = tr[62];

      acc[A_CMD_LOSS] += lseA - pA;
      acc[A_CMDC] += (c == pc) ? 1.f : 0.f;
      scmd[tid] = c;

      if (c == 1) {
        acc[A_NC] += 1.f;
        float bce = -(POSW * t62 * logsig(x62) + (1.f - t62) * logsig(-x62));
        acc[A_BCE] += bce;
        bool pos = (t62 == 1.f), neg = (t62 == 0.f);
        acc[A_NPOS] += pos ? 1.f : 0.f;
        acc[A_NNEG] += neg ? 1.f : 0.f;
        acc[A_POSC] += (pos && x62 > 0.f) ? 1.f : 0.f;
        acc[A_NEGC] += (neg && x62 <= 0.f) ? 1.f : 0.f;
        if (gr >= 1u) fl |= F_CUB;
        if (gr >= 2u) fl |= F_CUB2;
        mymin = (gr < mymin) ? gr : mymin;
      } else if (c == 2) {
        acc[A_NA] += 1.f;
        acc[A_CUBC] += (pc1 == c1 && pc2 == c2) ? 1.f : 0.f;
        acc[A_CE_AP] += (lseB - pB) + (lseC - pC);
        if (gr >= 1u) fl |= F_AP;
      } else if (c == 3) {
        acc[A_NREF] += 1.f;
        acc[A_REF_AX_CE] += lseE - pE;
        acc[A_REF_CUB_CE] += lseB - pB;
        acc[A_REF_AXC] += (pax == ax) ? 1.f : 0.f;
        acc[A_REF_CUBC] += (pc1 == c1) ? 1.f : 0.f;
        if (gr >= 1u) fl |= F_REF;
      } else if (c == 4) {
        acc[A_NTR] += 1.f;
        acc[A_TR_AX_CE] += lseE - pE;
        acc[A_TR_CUB_CE] += lseB - pB;
        acc[A_TR_AXC] += (pax == ax) ? 1.f : 0.f;
        acc[A_TR_CUBC] += (pc1 == c1) ? 1.f : 0.f;
        if (gr >= 1u) fl |= F_TR;
      } else if (c == 5) {
        acc[A_NSQ] += 1.f;
        acc[A_SQ_CUBC] += (pc1 == c1 && pc2 == c2 && pc3 == c3) ? 1.f : 0.f;
        acc[A_FACEC] += (fc == pfc) ? 1.f : 0.f;
        acc[A_SQ_CUB_CE] += (lseB - pB) + (lseC - pC) + (lseD - pD);
        acc[A_FACE_CE] += lseF - pF;
        if (gr >= 1u) fl |= F_SQ;
      }
    }
    asm volatile("s_waitcnt lgkmcnt(0)" ::: "memory");  // scmd visible to all waves
    __builtin_amdgcn_s_barrier();

    // ---- phase B: masked MAE (all 256 threads; W from regs, P/T from LDS) ----
    {
      const float4* sp4 = (const float4*)sp[cur];
      const float4* st4 = (const float4*)st[cur];
      #pragma unroll
      for (int k = 0; k < 4; ++k) {
        int i = tid + k * BLOCK;
        if (i < TILE_VEC4) {
          float4 w = wreg[k];
          float4 p = sp4[i];
          float4 t4v = st4[i];
          int e0 = i * 4;
          unsigned r0 = (unsigned)e0 / 63u;
          unsigned r3 = (unsigned)(e0 + 3) / 63u;
          int c0 = scmd[r0];
          int c3 = (r3 != r0) ? scmd[r3] : c0;
          float wv[4] = {w.x, w.y, w.z, w.w};
          float pv[4] = {p.x, p.y, p.z, p.w};
          float tv[4] = {t4v.x, t4v.y, t4v.z, t4v.w};
          #pragma unroll
          for (int q = 0; q < 4; ++q) {
            unsigned row = (unsigned)(e0 + q) / 63u;
            int c = (row == r0) ? c0 : c3;
            float v = wv[q] * fabsf(pv[q] - tv[q]);
            acc[A_MAE1] += (c == 1) ? v : 0.f;
            acc[A_MAE2] += (c == 2) ? v : 0.f;
            acc[A_MAE4] += (c == 4) ? v : 0.f;
            acc[A_MAE5] += (c == 5) ? v : 0.f;
          }
        }
      }
    }
    asm volatile("s_waitcnt lgkmcnt(0)" ::: "memory");  // LDS reads retired
    __builtin_amdgcn_s_barrier();  // protect buffer about to be DMA-overwritten
  }

  // ---- reduction: wave shuffle -> LDS -> atomics ----
  #pragma unroll
  for (int v = 0; v < NACC; ++v) {
    float x = acc[v];
    #pragma unroll
    for (int off = 32; off > 0; off >>= 1) x += __shfl_down(x, off, 64);
    if (lane == 0) sred[wave][v] = x;
  }
  {
    unsigned f = fl, m = mymin;
    #pragma unroll
    for (int off = 32; off > 0; off >>= 1) {
      f |= __shfl_down(f, off, 64);
      unsigned om = __shfl_down(m, off, 64);
      m = (om < m) ? om : m;
    }
    if (lane == 0) { sflags[wave] = f; smin[wave] = m; }
  }
  __syncthreads();
  unsigned* wu = (unsigned*)ws;
  if (tid == 0) {
    unsigned f = sflags[0] | sflags[1] | sflags[2] | sflags[3];
    unsigned m = min(min(smin[0], smin[1]), min(smin[2], smin[3]));
    if (f) atomicOr(&wu[NACC + 1], f);
    if (m != 0xFFFFFFFFu) atomicMin(&wu[NACC], m);
  }
  if (tid < NACC) {
    float s = sred[0][tid] + sred[1][tid] + sred[2][tid] + sred[3][tid];
    atomicAdd(&ws[tid], s);
  }
}

__global__ void finalize_k(const float* __restrict__ ws,
                           const float* __restrict__ P,
                           const float* __restrict__ T,
                           float* __restrict__ out) {
  const unsigned* wu = (const unsigned*)ws;
  unsigned flags = wu[NACC + 1];
  unsigned fm = wu[NACC];
  bool g_cub  = (flags & F_CUB)  != 0;
  bool g_cub2 = (flags & F_CUB2) != 0;
  bool g_ap   = (flags & F_AP)   != 0;
  bool g_ref  = (flags & F_REF)  != 0;
  bool g_tr   = (flags & F_TR)   != 0;
  bool g_sq   = (flags & F_SQ)   != 0;
  unsigned first = (fm == 0xFFFFFFFFu) ? 0u : fm;
  float x62 = P[(size_t)first * D_COLS + 62];
  float t62 = T[(size_t)first * D_COLS + 62];
  float bce_f = -(POSW * t62 * logsig(x62) + (1.f - t62) * logsig(-x62));
  float pos_f  = (t62 == 1.f) ? 1.f : 0.f;
  float neg_f  = (t62 == 0.f) ? 1.f : 0.f;
  float posc_f = (t62 == 1.f && x62 > 0.f) ? 1.f : 0.f;
  float negc_f = (t62 == 0.f && x62 <= 0.f) ? 1.f : 0.f;

  out[0]  = ws[A_CMD_LOSS];
  out[1]  = g_cub ? ws[A_MAE1] : 0.f;
  out[2]  = g_ap  ? ws[A_MAE2] : 0.f;
  out[3]  = g_sq  ? ws[A_MAE5] : 0.f;
  out[4]  = g_tr  ? ws[A_MAE4] : 0.f;
  out[5]  = g_ap  ? ws[A_CE_AP] : 0.f;
  out[6]  = g_sq  ? ws[A_SQ_CUB_CE] : 0.f;
  out[7]  = (g_ref ? ws[A_REF_CUB_CE] : 0.f) + (g_tr ? ws[A_TR_CUB_CE] : 0.f);
  out[8]  = (g_ref ? ws[A_REF_AX_CE]  : 0.f) + (g_tr ? ws[A_TR_AX_CE]  : 0.f);
  out[9]  = g_sq ? ws[A_FACE_CE] : 0.f;
  out[10] = ws[A_CMDC];
  out[11] = g_ap ? ws[A_CUBC] : 0.f;
  out[12] = g_sq ? ws[A_SQ_CUBC] : 0.f;
  out[13] = (g_ref ? ws[A_REF_CUBC] : 0.f) + (g_tr ? ws[A_TR_CUBC] : 0.f);
  out[14] = (g_ref ? ws[A_REF_AXC]  : 0.f) + (g_tr ? ws[A_TR_AXC]  : 0.f);
  out[15] = g_sq ? ws[A_FACEC] : 0.f;
  out[16] = g_cub2 ? (ws[A_BCE]  - bce_f)  : 0.f;
  out[17] = g_cub2 ? (ws[A_POSC] - posc_f) : 0.f;
  out[18] = g_cub2 ? (ws[A_NEGC] - negc_f) : 0.f;
  out[19] = g_cub2 ? (ws[A_NNEG] - neg_f)  : 0.f;
  out[20] = g_cub2 ? (ws[A_NPOS] - pos_f)  : 0.f;
  out[21] = ws[A_NA];
  out[22] = ws[A_NC];
  out[23] = ws[A_NREF] + ws[A_NTR];
  out[24] = ws[A_NSQ];
}

extern "C" void kernel_launch(void* const* d_in, const int* in_sizes, int n_in,
                              void* d_out, int out_size, void* d_ws, size_t ws_size,
                              hipStream_t stream) {
  const float* P = (const float*)d_in[0];
  const float* T = (const float*)d_in[1];
  const float* W = (const float*)d_in[2];
  float* ws = (float*)d_ws;
  float* out = (float*)d_out;

  hipLaunchKernelGGL(init_ws, dim3(1), dim3(64), 0, stream, ws);
  hipLaunchKernelGGL(prog_loss_main, dim3(GRID), dim3(BLOCK), 0, stream, P, T, W, ws);
  hipLaunchKernelGGL(finalize_k, dim3(1), dim3(1), 0, stream, ws, P, T, out);
}

// Round 5
// 103.218 us; speedup vs baseline: 1.9286x; 1.0892x over previous
//
#include <hip/hip_runtime.h>

#define S_ROWS 524288
#define D_COLS 63
#define TILE_ROWS 64
#define TILE_ELEMS (TILE_ROWS * D_COLS)   // 4032
#define TILE_VEC4 (TILE_ELEMS / 4)        // 1008
#define BLOCK 256
#define GRID 512
#define TILES_PER_BLOCK (S_ROWS / (TILE_ROWS * GRID))  // 16
#define NACC 30
#define POSW 0.2f

// gate flag bits
#define F_CUB  1u
#define F_CUB2 2u
#define F_AP   4u
#define F_REF  8u
#define F_TR   16u
#define F_SQ   32u

enum {
  A_CMD_LOSS = 0, A_CMDC, A_MAE1, A_MAE2, A_MAE4, A_MAE5,
  A_CE_AP, A_CUBC,
  A_REF_AX_CE, A_REF_CUB_CE, A_REF_AXC, A_REF_CUBC,
  A_TR_AX_CE, A_TR_CUB_CE, A_TR_AXC, A_TR_CUBC,
  A_SQ_CUB_CE, A_FACE_CE, A_SQ_CUBC, A_FACEC,
  A_BCE, A_NPOS, A_NNEG, A_POSC, A_NEGC,
  A_NA, A_NC, A_NREF, A_NTR, A_NSQ
};

#define GLOAD_LDS16(gptr, lptr) \
  __builtin_amdgcn_global_load_lds( \
      (const __attribute__((address_space(1))) void*)(gptr), \
      (__attribute__((address_space(3))) void*)(lptr), 16, 0, 0)

__device__ __forceinline__ float logsig(float x) {
  float ax = fabsf(x);
  return fminf(x, 0.f) - __logf(1.f + __expf(-ax));
}

__device__ __forceinline__ void slice_stats(const float* pr, const float* tr,
                                            int a, int b,
                                            int& targ, int& parg,
                                            float& lse, float& p_at_t) {
  float tmax = tr[a]; int ti = a;
  float pmax = pr[a]; int pi = a;
  #pragma unroll
  for (int j = a + 1; j < b; ++j) {
    float tv = tr[j]; if (tv > tmax) { tmax = tv; ti = j; }
    float pv = pr[j]; if (pv > pmax) { pmax = pv; pi = j; }
  }
  float se = 0.f;
  #pragma unroll
  for (int j = a; j < b; ++j) se += __expf(pr[j] - pmax);
  lse = pmax + __logf(se);
  targ = ti - a;
  parg = pi - a;
  p_at_t = pr[ti];
}

__global__ void init_ws(float* ws) {
  int i = threadIdx.x;
  if (i < NACC) ws[i] = 0.f;
  unsigned* wu = (unsigned*)ws;
  if (i == NACC) wu[NACC] = 0xFFFFFFFFu;
  if (i == NACC + 1) wu[NACC + 1] = 0u;
}

__device__ __forceinline__ void stage_tile(const float* __restrict__ gP,
                                           const float* __restrict__ gT,
                                           float* lp, float* lt,
                                           int tid, int wave) {
  const float4* P4 = (const float4*)gP;
  const float4* T4 = (const float4*)gT;
  #pragma unroll
  for (int k = 0; k < 4; ++k) {
    int i = tid + k * BLOCK;
    int chunk = wave * 64 + k * BLOCK;  // wave-uniform LDS f4 base; HW adds lane*16B
    if (i < TILE_VEC4) {
      GLOAD_LDS16(&P4[i], (float4*)lp + chunk);
      GLOAD_LDS16(&T4[i], (float4*)lt + chunk);
    }
  }
}

__launch_bounds__(BLOCK, 2)
__global__ void prog_loss_main(const float* __restrict__ P,
                               const float* __restrict__ T,
                               const float* __restrict__ W,
                               float* __restrict__ ws) {
  __shared__ float sp[2][TILE_ELEMS];
  __shared__ float st[2][TILE_ELEMS];
  __shared__ int scmd[TILE_ROWS];
  __shared__ int scok_c[TILE_ROWS];
  __shared__ int scok_d[TILE_ROWS];
  __shared__ float sred[4][NACC];
  __shared__ unsigned sflags[4];
  __shared__ unsigned smin[4];

  const int tid = threadIdx.x;
  const int lane = tid & 63;
  const int wave = tid >> 6;

  float acc[NACC];
  #pragma unroll
  for (int v = 0; v < NACC; ++v) acc[v] = 0.f;
  unsigned fl = 0u;
  unsigned mymin = 0xFFFFFFFFu;

  const int tile0 = blockIdx.x * TILES_PER_BLOCK;

  // prologue: stage first tile into buffer 0 (vmcnt = 8 at loop entry)
  stage_tile(P + (size_t)tile0 * TILE_ELEMS, T + (size_t)tile0 * TILE_ELEMS,
             sp[0], st[0], tid, wave);

  for (int tt = 0; tt < TILES_PER_BLOCK; ++tt) {
    const int tile = tile0 + tt;
    const int cur = tt & 1;
    const size_t base = (size_t)tile * TILE_ELEMS;

    // ---- W loads for CURRENT tile -> regs (covered by the counted vmcnt) ----
    float4 wreg[4];
    {
      const float4* W4 = (const float4*)(W + base);
      #pragma unroll
      for (int k = 0; k < 4; ++k) {
        int i = tid + k * BLOCK;
        if (i < TILE_VEC4) wreg[k] = W4[i];
        else wreg[k] = make_float4(0.f, 0.f, 0.f, 0.f);
      }
    }
    asm volatile("" ::: "memory");  // pin W loads before the DMA issue

    // ---- issue NEXT tile's DMA; counted wait keeps it in flight across barrier ----
    if (tt + 1 < TILES_PER_BLOCK) {
      const size_t nb = (size_t)(tile + 1) * TILE_ELEMS;
      stage_tile(P + nb, T + nb, sp[1 - cur], st[1 - cur], tid, wave);
      asm volatile("s_waitcnt vmcnt(8)" ::: "memory");
    } else {
      asm volatile("s_waitcnt vmcnt(0)" ::: "memory");
    }
    __builtin_amdgcn_sched_barrier(0);
    __builtin_amdgcn_s_barrier();

    // ============== phase A: column-split across the 4 waves, lane = row ==============
    int c_cmd;          // this lane's row command (all waves compute it)
    bool bok = false;   // wave0: slice-B argmax match, used post-barrier
    {
      const int row = lane;
      const float* pr = sp[cur] + row * D_COLS;
      const float* tr = st[cur] + row * D_COLS;
      const unsigned gr = (unsigned)(tile * TILE_ROWS + row);

      if (wave != 3) {
        // cmd = argmax T[:, 0:7] (T-only, 7 LDS reads)
        float tm = tr[0]; int c = 0;
        #pragma unroll
        for (int j = 1; j < 7; ++j) {
          float tv = tr[j]; if (tv > tm) { tm = tv; c = j; }
        }
        c_cmd = c;
      }

      if (wave == 0) {
        int c1, pc1; float lseB, pB; slice_stats(pr, tr, 7, 18, c1, pc1, lseB, pB);
        bok = (pc1 == c1);
        float ceB = lseB - pB;
        int c = c_cmd;
        if (c == 2)      acc[A_CE_AP] += ceB;
        else if (c == 3) { acc[A_REF_CUB_CE] += ceB; acc[A_REF_CUBC] += bok ? 1.f : 0.f; }
        else if (c == 4) { acc[A_TR_CUB_CE]  += ceB; acc[A_TR_CUBC]  += bok ? 1.f : 0.f; }
        else if (c == 5) acc[A_SQ_CUB_CE] += ceB;
      } else if (wave == 1) {
        int c2, pc2; float lseC, pC; slice_stats(pr, tr, 18, 29, c2, pc2, lseC, pC);
        scok_c[row] = (pc2 == c2) ? 1 : 0;
        float ceC = lseC - pC;
        int c = c_cmd;
        if (c == 2)      acc[A_CE_AP] += ceC;
        else if (c == 5) acc[A_SQ_CUB_CE] += ceC;
      } else if (wave == 2) {
        int c3, pc3; float lseD, pD; slice_stats(pr, tr, 29, 40, c3, pc3, lseD, pD);
        scok_d[row] = (pc3 == c3) ? 1 : 0;
        if (c_cmd == 5) acc[A_SQ_CUB_CE] += lseD - pD;
      } else {
        // wave 3: slice A (cmd_loss/cmdc), E, F, col 62, counts, flags, first-row min
        int c, pc0; float lseA, pA; slice_stats(pr, tr, 0, 7, c, pc0, lseA, pA);
        c_cmd = c;
        int ax, pax; float lseE, pE; slice_stats(pr, tr, 49, 52, ax, pax, lseE, pE);
        int fc, pfc; float lseF, pF; slice_stats(pr, tr, 54, 60, fc, pfc, lseF, pF);
        float x62 = pr[62], t62 = tr[62];

        acc[A_CMD_LOSS] += lseA - pA;
        acc[A_CMDC] += (c == pc0) ? 1.f : 0.f;
        scmd[row] = c;

        if (c == 1) {
          acc[A_NC] += 1.f;
          float bce = -(POSW * t62 * logsig(x62) + (1.f - t62) * logsig(-x62));
          acc[A_BCE] += bce;
          bool pos = (t62 == 1.f), neg = (t62 == 0.f);
          acc[A_NPOS] += pos ? 1.f : 0.f;
          acc[A_NNEG] += neg ? 1.f : 0.f;
          acc[A_POSC] += (pos && x62 > 0.f) ? 1.f : 0.f;
          acc[A_NEGC] += (neg && x62 <= 0.f) ? 1.f : 0.f;
          if (gr >= 1u) fl |= F_CUB;
          if (gr >= 2u) fl |= F_CUB2;
          mymin = (gr < mymin) ? gr : mymin;
        } else if (c == 2) {
          acc[A_NA] += 1.f;
          if (gr >= 1u) fl |= F_AP;
        } else if (c == 3) {
          acc[A_NREF] += 1.f;
          acc[A_REF_AX_CE] += lseE - pE;
          acc[A_REF_AXC] += (pax == ax) ? 1.f : 0.f;
          if (gr >= 1u) fl |= F_REF;
        } else if (c == 4) {
          acc[A_NTR] += 1.f;
          acc[A_TR_AX_CE] += lseE - pE;
          acc[A_TR_AXC] += (pax == ax) ? 1.f : 0.f;
          if (gr >= 1u) fl |= F_TR;
        } else if (c == 5) {
          acc[A_NSQ] += 1.f;
          acc[A_FACEC] += (fc == pfc) ? 1.f : 0.f;
          acc[A_FACE_CE] += lseF - pF;
          if (gr >= 1u) fl |= F_SQ;
        }
      }
    }
    asm volatile("s_waitcnt lgkmcnt(0)" ::: "memory");  // scmd/scok visible
    __builtin_amdgcn_s_barrier();

    // ---- wave0: joint-argmax counters (needs c_ok/d_ok from waves 1,2) ----
    if (wave == 0) {
      int cok = scok_c[lane];
      int dok = scok_d[lane];
      if (c_cmd == 2)      acc[A_CUBC]    += (bok && cok) ? 1.f : 0.f;
      else if (c_cmd == 5) acc[A_SQ_CUBC] += (bok && cok && dok) ? 1.f : 0.f;
    }

    // ---- phase B: masked MAE (all 256 threads; W from regs, P/T from LDS) ----
    {
      const float4* sp4 = (const float4*)sp[cur];
      const float4* st4 = (const float4*)st[cur];
      #pragma unroll
      for (int k = 0; k < 4; ++k) {
        int i = tid + k * BLOCK;
        if (i < TILE_VEC4) {
          float4 w = wreg[k];
          float4 p = sp4[i];
          float4 t4v = st4[i];
          int e0 = i * 4;
          unsigned r0 = (unsigned)e0 / 63u;
          unsigned r3 = (unsigned)(e0 + 3) / 63u;
          int c0 = scmd[r0];
          int c3 = (r3 != r0) ? scmd[r3] : c0;
          float wv[4] = {w.x, w.y, w.z, w.w};
          float pv[4] = {p.x, p.y, p.z, p.w};
          float tv[4] = {t4v.x, t4v.y, t4v.z, t4v.w};
          #pragma unroll
          for (int q = 0; q < 4; ++q) {
            unsigned row = (unsigned)(e0 + q) / 63u;
            int c = (row == r0) ? c0 : c3;
            float v = wv[q] * fabsf(pv[q] - tv[q]);
            acc[A_MAE1] += (c == 1) ? v : 0.f;
            acc[A_MAE2] += (c == 2) ? v : 0.f;
            acc[A_MAE4] += (c == 4) ? v : 0.f;
            acc[A_MAE5] += (c == 5) ? v : 0.f;
          }
        }
      }
    }
    asm volatile("s_waitcnt lgkmcnt(0)" ::: "memory");  // LDS reads retired
    __builtin_amdgcn_s_barrier();  // protect buffer about to be DMA-overwritten
  }

  // ---- reduction: wave shuffle -> LDS -> atomics ----
  #pragma unroll
  for (int v = 0; v < NACC; ++v) {
    float x = acc[v];
    #pragma unroll
    for (int off = 32; off > 0; off >>= 1) x += __shfl_down(x, off, 64);
    if (lane == 0) sred[wave][v] = x;
  }
  {
    unsigned f = fl, m = mymin;
    #pragma unroll
    for (int off = 32; off > 0; off >>= 1) {
      f |= __shfl_down(f, off, 64);
      unsigned om = __shfl_down(m, off, 64);
      m = (om < m) ? om : m;
    }
    if (lane == 0) { sflags[wave] = f; smin[wave] = m; }
  }
  __syncthreads();
  unsigned* wu = (unsigned*)ws;
  if (tid == 0) {
    unsigned f = sflags[0] | sflags[1] | sflags[2] | sflags[3];
    unsigned m = min(min(smin[0], smin[1]), min(smin[2], smin[3]));
    if (f) atomicOr(&wu[NACC + 1], f);
    if (m != 0xFFFFFFFFu) atomicMin(&wu[NACC], m);
  }
  if (tid < NACC) {
    float s = sred[0][tid] + sred[1][tid] + sred[2][tid] + sred[3][tid];
    atomicAdd(&ws[tid], s);
  }
}

__global__ void finalize_k(const float* __restrict__ ws,
                           const float* __restrict__ P,
                           const float* __restrict__ T,
                           float* __restrict__ out) {
  const unsigned* wu = (const unsigned*)ws;
  unsigned flags = wu[NACC + 1];
  unsigned fm = wu[NACC];
  bool g_cub  = (flags & F_CUB)  != 0;
  bool g_cub2 = (flags & F_CUB2) != 0;
  bool g_ap   = (flags & F_AP)   != 0;
  bool g_ref  = (flags & F_REF)  != 0;
  bool g_tr   = (flags & F_TR)   != 0;
  bool g_sq   = (flags & F_SQ)   != 0;
  unsigned first = (fm == 0xFFFFFFFFu) ? 0u : fm;
  float x62 = P[(size_t)first * D_COLS + 62];
  float t62 = T[(size_t)first * D_COLS + 62];
  float bce_f = -(POSW * t62 * logsig(x62) + (1.f - t62) * logsig(-x62));
  float pos_f  = (t62 == 1.f) ? 1.f : 0.f;
  float neg_f  = (t62 == 0.f) ? 1.f : 0.f;
  float posc_f = (t62 == 1.f && x62 > 0.f) ? 1.f : 0.f;
  float negc_f = (t62 == 0.f && x62 <= 0.f) ? 1.f : 0.f;

  out[0]  = ws[A_CMD_LOSS];
  out[1]  = g_cub ? ws[A_MAE1] : 0.f;
  out[2]  = g_ap  ? ws[A_MAE2] : 0.f;
  out[3]  = g_sq  ? ws[A_MAE5] : 0.f;
  out[4]  = g_tr  ? ws[A_MAE4] : 0.f;
  out[5]  = g_ap  ? ws[A_CE_AP] : 0.f;
  out[6]  = g_sq  ? ws[A_SQ_CUB_CE] : 0.f;
  out[7]  = (g_ref ? ws[A_REF_CUB_CE] : 0.f) + (g_tr ? ws[A_TR_CUB_CE] : 0.f);
  out[8]  = (g_ref ? ws[A_REF_AX_CE]  : 0.f) + (g_tr ? ws[A_TR_AX_CE]  : 0.f);
  out[9]  = g_sq ? ws[A_FACE_CE] : 0.f;
  out[10] = ws[A_CMDC];
  out[11] = g_ap ? ws[A_CUBC] : 0.f;
  out[12] = g_sq ? ws[A_SQ_CUBC] : 0.f;
  out[13] = (g_ref ? ws[A_REF_CUBC] : 0.f) + (g_tr ? ws[A_TR_CUBC] : 0.f);
  out[14] = (g_ref ? ws[A_REF_AXC]  : 0.f) + (g_tr ? ws[A_TR_AXC]  : 0.f);
  out[15] = g_sq ? ws[A_FACEC] : 0.f;
  out[16] = g_cub2 ? (ws[A_BCE]  - bce_f)  : 0.f;
  out[17] = g_cub2 ? (ws[A_POSC] - posc_f) : 0.f;
  out[18] = g_cub2 ? (ws[A_NEGC] - negc_f) : 0.f;
  out[19] = g_cub2 ? (ws[A_NNEG] - neg_f)  : 0.f;
  out[20] = g_cub2 ? (ws[A_NPOS] - pos_f)  : 0.f;
  out[21] = ws[A_NA];
  out[22] = ws[A_NC];
  out[23] = ws[A_NREF] + ws[A_NTR];
  out[24] = ws[A_NSQ];
}

extern "C" void kernel_launch(void* const* d_in, const int* in_sizes, int n_in,
                              void* d_out, int out_size, void* d_ws, size_t ws_size,
                              hipStream_t stream) {
  const float* P = (const float*)d_in[0];
  const float* T = (const float*)d_in[1];
  const float* W = (const float*)d_in[2];
  float* ws = (float*)d_ws;
  float* out = (float*)d_out;

  hipLaunchKernelGGL(init_ws, dim3(1), dim3(64), 0, stream, ws);
  hipLaunchKernelGGL(prog_loss_main, dim3(GRID), dim3(BLOCK), 0, stream, P, T, W, ws);
  hipLaunchKernelGGL(finalize_k, dim3(1), dim3(1), 0, stream, ws, P, T, out);
}